// Round 6
// baseline (47.845 us; speedup 1.0000x reference)
//
#include <hip/hip_runtime.h>
#include <hip/hip_bf16.h>

#define NB 32
#define NP 4096
#define NC 128
#define ND 128
#define TP 128            // points per block
#define EPSV 1e-16f

typedef __attribute__((ext_vector_type(8))) short short8;
typedef __attribute__((ext_vector_type(4))) float f32x4;

__device__ __forceinline__ unsigned short f2bf(float f) {
  __hip_bfloat16 h = __float2bfloat16(f);
  return *reinterpret_cast<unsigned short*>(&h);
}

// LDS byte-offset swizzle: row-major [row][128 bf16] with XOR of (row&7)<<4.
__device__ __forceinline__ int swz(int row, int kbyte) {
  return (row * 256 + kbyte) ^ ((row & 7) << 4);
}

// Pre-kernel: pre-swizzled bf16 codes^T images ([d][c]) for the 32 gathered
// records -> d_ws. 256 blocks (8 per record), 256 threads.
__global__ void cc_pre(const int* __restrict__ indices,
                       const float* __restrict__ codes,
                       unsigned char* __restrict__ ws) {
  const int b = blockIdx.x >> 3;
  const int chunk = blockIdx.x & 7;
  const int rec = indices[b];
  const float* cb = codes + (size_t)rec * (NC * ND);
  unsigned char* wb = ws + (size_t)b * (NC * ND * 2);
  const int tid = threadIdx.x;        // 256 threads
  const int d = chunk * 16 + (tid & 15);
  const int c0 = (tid >> 4) * 8;      // 8 consecutive codes
  short8 v;
  #pragma unroll
  for (int j = 0; j < 8; ++j)
    v[j] = (short)f2bf(cb[(size_t)(c0 + j) * ND + d]);
  *(short8*)(wb + swz(d, c0 * 2)) = v;
}

// Main kernel, round 6: wT eliminated. Phase 2 recomputes its B-fragment
// (weights) in-register from LDS-staged code positions + per-point inv-sum,
// with ops/order identical to phase 1 -> bit-identical bf16 weights.
// LDS 64KB -> ~35KB, LB(256,4): 4 blocks/CU, whole grid co-resident.
template<bool PRE>
__global__ __launch_bounds__(256, 4) void cc_main(
    const int* __restrict__ indices,
    const float* __restrict__ qp,       // (B,P,3)
    const float* __restrict__ cpos,     // (R,C,3)
    const float* __restrict__ codes,    // (R,C,D)
    const void* __restrict__ dsp,       // dist_scale scalar
    const unsigned char* __restrict__ wsc, // pre-swizzled bf16 cT images
    float* __restrict__ out_qc,         // (B,P,D)
    float* __restrict__ out_sq,         // (B,P,C)
    float* __restrict__ out_wt) {       // (B,P,C)
  __shared__ __align__(16) unsigned char cT[ND * NC * 2];   // 32KB
  __shared__ __align__(16) float pos4[NC][4];               // 2KB
  __shared__ float isum[TP];                                // 512B

  const int tid = threadIdx.x;
  const int lane = tid & 63;
  const int wv = tid >> 6;
  const int g = lane >> 4;            // point-within-quad (phase 1)
  const int l16 = lane & 15;
  const int c0 = l16 * 8;             // this lane's 8 codes (phase 1)
  const int b = blockIdx.x >> 5;
  const int p0 = (blockIdx.x & 31) * TP;
  const int rec = indices[b];

  const int si = ((const int*)dsp)[0];
  const float sv = (si > 0 && si < 1000) ? (float)si : ((const float*)dsp)[0];

  // ---- stage code positions into LDS (consumed by phase 2 after the barrier)
  if (tid < NC) {
    const float* cp = cpos + ((size_t)rec * NC + tid) * 3;
    pos4[tid][0] = cp[0]; pos4[tid][1] = cp[1]; pos4[tid][2] = cp[2];
    pos4[tid][3] = 0.f;
  }

  // ---- phase-1 positions in registers (independent loads, single latency)
  const float* pb = cpos + ((size_t)rec * NC + c0) * 3;
  float px[8], py[8], pz[8];
  #pragma unroll
  for (int j = 0; j < 8; ++j) {
    px[j] = pb[j * 3 + 0]; py[j] = pb[j * 3 + 1]; pz[j] = pb[j * 3 + 2];
  }

  const size_t rowbase = (size_t)b * NP + p0;
  float qx[8], qy[8], qz[8];
  #pragma unroll
  for (int it = 0; it < 8; ++it) {
    const int p = it * 16 + wv * 4 + g;
    const float* q = qp + (rowbase + p) * 3;
    qx[it] = q[0]; qy[it] = q[1]; qz[it] = q[2];
  }

  // ---- phase-2 q rows for this lane (L2-hot after phase-1 touch; hoisted)
  const int pr0 = wv * 32 + l16;
  const float* qq0 = qp + (rowbase + pr0) * 3;
  const float* qq1 = qp + (rowbase + pr0 + 16) * 3;
  const float q0x = qq0[0], q0y = qq0[1], q0z = qq0[2];
  const float q1x = qq1[0], q1y = qq1[1], q1z = qq1[2];

  // ---- cT staging: DMA issued after the register loads; drains at the
  // barrier, fully overlapped with phase 1.
  if (PRE) {
    const unsigned char* src = wsc + (size_t)b * (NC * ND * 2);
    #pragma unroll
    for (int it = 0; it < 8; ++it) {
      const int off = (wv * 8 + it) * 1024;
      __builtin_amdgcn_global_load_lds(
          (const __attribute__((address_space(1))) void*)(src + off + lane * 16),
          (__attribute__((address_space(3))) void*)(cT + off),
          16, 0, 0);
    }
  } else {
    const float* cb = codes + (size_t)rec * (NC * ND);
    #pragma unroll
    for (int it = 0; it < 16; ++it) {
      int i = tid * 4 + it * 1024;
      float4 v = *reinterpret_cast<const float4*>(cb + i);
      int c = i >> 7, d0 = i & 127;
      float vv[4] = {v.x, v.y, v.z, v.w};
      #pragma unroll
      for (int j = 0; j < 4; ++j)
        *(unsigned short*)(cT + swz(d0 + j, c * 2)) = f2bf(vv[j]);
    }
  }

  // ---- phase 1: 4 points per wave in flight; lane owns 8 codes.
  const bool s2 = (sv == 2.0f);
  #pragma unroll
  for (int it = 0; it < 8; ++it) {
    const int p = it * 16 + wv * 4 + g;
    float dd[8], wu[8];
    #pragma unroll
    for (int j = 0; j < 8; ++j) {
      const float dx = qx[it] - px[j], dy = qy[it] - py[j], dz = qz[it] - pz[j];
      dd[j] = fmaf(dx, dx, fmaf(dy, dy, dz * dz)) + EPSV;
    }
    if (s2) {
      #pragma unroll
      for (int j = 0; j < 8; ++j) wu[j] = __builtin_amdgcn_rcpf(dd[j]);
    } else {
      #pragma unroll
      for (int j = 0; j < 8; ++j) wu[j] = __powf(dd[j], -0.5f * sv);
    }
    float s = ((wu[0] + wu[1]) + (wu[2] + wu[3])) + ((wu[4] + wu[5]) + (wu[6] + wu[7]));
    s += __shfl_xor(s, 1); s += __shfl_xor(s, 2);
    s += __shfl_xor(s, 4); s += __shfl_xor(s, 8);   // within 16-lane group
    const float inv = __builtin_amdgcn_rcpf(s);
    if (l16 == 0) isum[p] = inv;                    // phase-2 consumes

    f32x4 dlo, dhi, wlo, whi;
    #pragma unroll
    for (int j = 0; j < 4; ++j) {
      dlo[j] = dd[j]; dhi[j] = dd[j + 4];
      wlo[j] = wu[j] * inv; whi[j] = wu[j + 4] * inv;
    }
    const size_t rb = (rowbase + p) * (size_t)NC + c0;
    *(f32x4*)(out_sq + rb) = dlo;
    *(f32x4*)(out_sq + rb + 4) = dhi;
    *(f32x4*)(out_wt + rb) = wlo;
    *(f32x4*)(out_wt + rb + 4) = whi;
  }

  __syncthreads();   // drains stores + cT DMA + pos4/isum writes

  // ---- phase 2: MFMA, swapped operands (D[d][p], validated round 4/5).
  // B-fragments recomputed in-register: w[pr][c] = f2bf(rcp(dist)*inv) —
  // identical ops/order to phase 1 -> bit-identical to the old wT values.
  const int kg = lane >> 4;
  const float inv0 = isum[pr0];
  const float inv1 = isum[pr0 + 16];
  f32x4 acc[2][8];
  #pragma unroll
  for (int pi = 0; pi < 2; ++pi)
    #pragma unroll
    for (int mi = 0; mi < 8; ++mi)
      acc[pi][mi] = (f32x4){0.f, 0.f, 0.f, 0.f};

  #pragma unroll
  for (int kk = 0; kk < 4; ++kk) {
    const int cbase = kk * 32 + kg * 8;
    short8 bf0, bf1;
    #pragma unroll
    for (int j = 0; j < 8; ++j) {
      const float4 pc = *(const float4*)&pos4[cbase + j][0];
      float dx = q0x - pc.x, dy = q0y - pc.y, dz = q0z - pc.z;
      const float d0 = fmaf(dx, dx, fmaf(dy, dy, dz * dz)) + EPSV;
      dx = q1x - pc.x; dy = q1y - pc.y; dz = q1z - pc.z;
      const float d1 = fmaf(dx, dx, fmaf(dy, dy, dz * dz)) + EPSV;
      float w0, w1;
      if (s2) { w0 = __builtin_amdgcn_rcpf(d0); w1 = __builtin_amdgcn_rcpf(d1); }
      else    { w0 = __powf(d0, -0.5f * sv);    w1 = __powf(d1, -0.5f * sv); }
      bf0[j] = (short)f2bf(w0 * inv0);
      bf1[j] = (short)f2bf(w1 * inv1);
    }
    const int kb = cbase * 2;
    #pragma unroll
    for (int mi = 0; mi < 8; ++mi) {
      const short8 a8 = *(const short8*)(cT + swz(mi * 16 + l16, kb));
      acc[0][mi] = __builtin_amdgcn_mfma_f32_16x16x32_bf16(a8, bf0, acc[0][mi], 0, 0, 0);
      acc[1][mi] = __builtin_amdgcn_mfma_f32_16x16x32_bf16(a8, bf1, acc[1][mi], 0, 0, 0);
    }
  }

  // D layout: col(=p-offset) = lane&15, row(=d-offset) = (lane>>4)*4 + reg
  float* o0 = out_qc + (rowbase + pr0) * (size_t)ND + kg * 4;
  float* o1 = out_qc + (rowbase + pr0 + 16) * (size_t)ND + kg * 4;
  #pragma unroll
  for (int mi = 0; mi < 8; ++mi) {
    *(f32x4*)(o0 + mi * 16) = acc[0][mi];
    *(f32x4*)(o1 + mi * 16) = acc[1][mi];
  }
}

extern "C" void kernel_launch(void* const* d_in, const int* in_sizes, int n_in,
                              void* d_out, int out_size, void* d_ws, size_t ws_size,
                              hipStream_t stream) {
  const int* indices = (const int*)d_in[0];
  const float* qp = (const float*)d_in[1];
  const float* cpos = (const float*)d_in[2];
  const float* codes = (const float*)d_in[3];
  const void* dsp = d_in[4];

  float* out = (float*)d_out;
  float* qc = out;                                   // (B,P,D)
  float* sq = qc + (size_t)NB * NP * ND;             // (B,P,C)
  float* wt = sq + (size_t)NB * NP * NC;             // (B,P,C)

  const size_t ws_need = (size_t)NB * NC * ND * 2;   // 1 MiB
  dim3 grid(NB * (NP / TP));
  if (ws_size >= ws_need) {
    cc_pre<<<dim3(NB * 8), dim3(256), 0, stream>>>(indices, codes, (unsigned char*)d_ws);
    cc_main<true><<<grid, 256, 0, stream>>>(indices, qp, cpos, codes, dsp,
                                            (const unsigned char*)d_ws, qc, sq, wt);
  } else {
    cc_main<false><<<grid, 256, 0, stream>>>(indices, qp, cpos, codes, dsp,
                                             nullptr, qc, sq, wt);
  }
}

// Round 7
// 44.532 us; speedup vs baseline: 1.0744x; 1.0744x over previous
//
#include <hip/hip_runtime.h>
#include <hip/hip_bf16.h>

#define NB 32
#define NP 4096
#define NC 128
#define ND 128
#define TP 128            // points per block (32 per wave)
#define EPSV 1e-16f

typedef __attribute__((ext_vector_type(8))) short short8;
typedef __attribute__((ext_vector_type(4))) short short4v;
typedef __attribute__((ext_vector_type(4))) float f32x4;

__device__ __forceinline__ unsigned short f2bf(float f) {
  __hip_bfloat16 h = __float2bfloat16(f);
  return *reinterpret_cast<unsigned short*>(&h);
}

// LDS byte-offset swizzle: row-major [row][128 bf16] with XOR of (row&7)<<4.
// XOR touches bits 4-6 only -> aligned 8B/16B accesses stay contiguous.
__device__ __forceinline__ int swz(int row, int kbyte) {
  return (row * 256 + kbyte) ^ ((row & 7) << 4);
}

// Pre-kernel: pre-swizzled bf16 codes^T images ([d][c]) for the 32 gathered
// records -> d_ws. 256 blocks (8 per record), 256 threads.
__global__ void cc_pre(const int* __restrict__ indices,
                       const float* __restrict__ codes,
                       unsigned char* __restrict__ ws) {
  const int b = blockIdx.x >> 3;
  const int chunk = blockIdx.x & 7;
  const int rec = indices[b];
  const float* cb = codes + (size_t)rec * (NC * ND);
  unsigned char* wb = ws + (size_t)b * (NC * ND * 2);
  const int tid = threadIdx.x;        // 256 threads
  const int d = chunk * 16 + (tid & 15);
  const int c0 = (tid >> 4) * 8;      // 8 consecutive codes
  short8 v;
  #pragma unroll
  for (int j = 0; j < 8; ++j)
    v[j] = (short)f2bf(cb[(size_t)(c0 + j) * ND + d]);
  *(short8*)(wb + swz(d, c0 * 2)) = v;
}

// Round 7: barrier-free main structure. Phase-1 wave wv owns points
// wv*32..wv*32+31 (same points its phase 2 outputs) -> wT is per-wave
// (4 x 8KB sections), cross-lane only within the wave (lgkmcnt, lockstep,
// no s_barrier). The single barrier sits BEFORE phase 1 and drains only the
// cT DMA + register loads — phase-1's 128KB store burst never blocks a
// barrier; it drains under phase-2 MFMA.
template<bool PRE>
__global__ __launch_bounds__(256, 2) void cc_main(
    const int* __restrict__ indices,
    const float* __restrict__ qp,       // (B,P,3)
    const float* __restrict__ cpos,     // (R,C,3)
    const float* __restrict__ codes,    // (R,C,D)
    const void* __restrict__ dsp,       // dist_scale scalar
    const unsigned char* __restrict__ wsc, // pre-swizzled bf16 cT images
    float* __restrict__ out_qc,         // (B,P,D)
    float* __restrict__ out_sq,         // (B,P,C)
    float* __restrict__ out_wt) {       // (B,P,C)
  __shared__ __align__(16) unsigned char cT[ND * NC * 2];   // 32KB shared
  __shared__ __align__(16) unsigned char wT[TP * NC * 2];   // 32KB, 8KB/wave

  const int tid = threadIdx.x;
  const int lane = tid & 63;
  const int wv = tid >> 6;
  const int g = lane >> 4;            // point-within-quad (phase 1)
  const int l16 = lane & 15;
  const int b = blockIdx.x >> 5;
  const int p0 = (blockIdx.x & 31) * TP;
  const int rec = indices[b];
  unsigned char* wTw = wT + wv * 8192; // this wave's 32-row section

  const int si = ((const int*)dsp)[0];
  const float sv = (si > 0 && si < 1000) ? (float)si : ((const float*)dsp)[0];

  // ---- cT staging first (DMA for PRE; inline else), so the early barrier
  // covers it.
  if (PRE) {
    const unsigned char* src = wsc + (size_t)b * (NC * ND * 2);
    #pragma unroll
    for (int it = 0; it < 8; ++it) {
      const int off = (wv * 8 + it) * 1024;
      __builtin_amdgcn_global_load_lds(
          (const __attribute__((address_space(1))) void*)(src + off + lane * 16),
          (__attribute__((address_space(3))) void*)(cT + off),
          16, 0, 0);
    }
  } else {
    const float* cb = codes + (size_t)rec * (NC * ND);
    #pragma unroll
    for (int it = 0; it < 16; ++it) {
      int i = tid * 4 + it * 1024;
      float4 v = *reinterpret_cast<const float4*>(cb + i);
      int c = i >> 7, d0 = i & 127;
      float vv[4] = {v.x, v.y, v.z, v.w};
      #pragma unroll
      for (int j = 0; j < 4; ++j)
        *(unsigned short*)(cT + swz(d0 + j, c * 2)) = f2bf(vv[j]);
    }
  }

  // ---- per-lane code positions: lane owns codes l16*4..+3 and 64+l16*4..+3
  // (dense-store ownership: each f32x4 store is a contiguous 256B/group run)
  const float* pb0 = cpos + ((size_t)rec * NC + l16 * 4) * 3;
  const float* pb1 = cpos + ((size_t)rec * NC + 64 + l16 * 4) * 3;
  float px[8], py[8], pz[8];
  #pragma unroll
  for (int j = 0; j < 4; ++j) {
    px[j] = pb0[j * 3 + 0]; py[j] = pb0[j * 3 + 1]; pz[j] = pb0[j * 3 + 2];
    px[j + 4] = pb1[j * 3 + 0]; py[j + 4] = pb1[j * 3 + 1]; pz[j + 4] = pb1[j * 3 + 2];
  }

  // ---- q for this wave's 32 points: p = wv*32 + it*4 + g
  const size_t rowbase = (size_t)b * NP + p0;
  float qx[8], qy[8], qz[8];
  #pragma unroll
  for (int it = 0; it < 8; ++it) {
    const int p = wv * 32 + it * 4 + g;
    const float* q = qp + (rowbase + p) * 3;
    qx[it] = q[0]; qy[it] = q[1]; qz[it] = q[2];
  }

  __syncthreads();   // ONLY barrier: drains cT DMA + the register loads.
                     // Zero global stores are in flight here.

  // ---- phase 1: wave-local points; lane owns 8 codes (4+4 split).
  const bool s2 = (sv == 2.0f);
  #pragma unroll
  for (int it = 0; it < 8; ++it) {
    const int p = wv * 32 + it * 4 + g;
    float dd[8], wu[8];
    #pragma unroll
    for (int j = 0; j < 8; ++j) {
      const float dx = qx[it] - px[j], dy = qy[it] - py[j], dz = qz[it] - pz[j];
      dd[j] = fmaf(dx, dx, fmaf(dy, dy, dz * dz)) + EPSV;
    }
    if (s2) {
      #pragma unroll
      for (int j = 0; j < 8; ++j) wu[j] = __builtin_amdgcn_rcpf(dd[j]);
    } else {
      #pragma unroll
      for (int j = 0; j < 8; ++j) wu[j] = __powf(dd[j], -0.5f * sv);
    }
    float s = ((wu[0] + wu[1]) + (wu[2] + wu[3])) + ((wu[4] + wu[5]) + (wu[6] + wu[7]));
    s += __shfl_xor(s, 1); s += __shfl_xor(s, 2);
    s += __shfl_xor(s, 4); s += __shfl_xor(s, 8);   // within 16-lane group
    const float inv = __builtin_amdgcn_rcpf(s);

    f32x4 dlo, dhi, wlo, whi;
    #pragma unroll
    for (int j = 0; j < 4; ++j) {
      dlo[j] = dd[j]; dhi[j] = dd[j + 4];
      wlo[j] = wu[j] * inv; whi[j] = wu[j + 4] * inv;
    }
    const size_t rb = (rowbase + p) * (size_t)NC;
    *(f32x4*)(out_sq + rb + l16 * 4) = dlo;
    *(f32x4*)(out_sq + rb + 64 + l16 * 4) = dhi;
    *(f32x4*)(out_wt + rb + l16 * 4) = wlo;
    *(f32x4*)(out_wt + rb + 64 + l16 * 4) = whi;

    // bf16 weights -> this wave's wT section (local row = it*4+g)
    short4v wbl, wbh;
    #pragma unroll
    for (int j = 0; j < 4; ++j) {
      wbl[j] = (short)f2bf(wlo[j]);
      wbh[j] = (short)f2bf(whi[j]);
    }
    const int r = it * 4 + g;
    *(short4v*)(wTw + swz(r, l16 * 8)) = wbl;        // codes l16*4..+3
    *(short4v*)(wTw + swz(r, 128 + l16 * 8)) = wbh;  // codes 64+l16*4..+3
  }

  // ---- NO barrier: phase 2 reads only this wave's wT (lgkmcnt, lockstep)
  // and cT (synced at the early barrier). Phase-1 stores drain underneath.

  const int kg = lane >> 4;
  const int pr0 = wv * 32 + l16;       // this lane's two points
  f32x4 acc[2][8];
  #pragma unroll
  for (int pi = 0; pi < 2; ++pi)
    #pragma unroll
    for (int mi = 0; mi < 8; ++mi)
      acc[pi][mi] = (f32x4){0.f, 0.f, 0.f, 0.f};

  #pragma unroll
  for (int kk = 0; kk < NC; kk += 32) {
    const int kb = (kk + kg * 8) * 2;
    const short8 b0 = *(const short8*)(wTw + swz(l16, kb));
    const short8 b1 = *(const short8*)(wTw + swz(l16 + 16, kb));
    #pragma unroll
    for (int mi = 0; mi < 8; ++mi) {
      const short8 a8 = *(const short8*)(cT + swz(mi * 16 + l16, kb));
      acc[0][mi] = __builtin_amdgcn_mfma_f32_16x16x32_bf16(a8, b0, acc[0][mi], 0, 0, 0);
      acc[1][mi] = __builtin_amdgcn_mfma_f32_16x16x32_bf16(a8, b1, acc[1][mi], 0, 0, 0);
    }
  }

  // D layout: col(=p-offset) = lane&15, row(=d-offset) = (lane>>4)*4 + reg
  float* o0 = out_qc + (rowbase + pr0) * (size_t)ND + kg * 4;
  float* o1 = out_qc + (rowbase + pr0 + 16) * (size_t)ND + kg * 4;
  #pragma unroll
  for (int mi = 0; mi < 8; ++mi) {
    *(f32x4*)(o0 + mi * 16) = acc[0][mi];
    *(f32x4*)(o1 + mi * 16) = acc[1][mi];
  }

  (void)codes;
}

extern "C" void kernel_launch(void* const* d_in, const int* in_sizes, int n_in,
                              void* d_out, int out_size, void* d_ws, size_t ws_size,
                              hipStream_t stream) {
  const int* indices = (const int*)d_in[0];
  const float* qp = (const float*)d_in[1];
  const float* cpos = (const float*)d_in[2];
  const float* codes = (const float*)d_in[3];
  const void* dsp = d_in[4];

  float* out = (float*)d_out;
  float* qc = out;                                   // (B,P,D)
  float* sq = qc + (size_t)NB * NP * ND;             // (B,P,C)
  float* wt = sq + (size_t)NB * NP * NC;             // (B,P,C)

  const size_t ws_need = (size_t)NB * NC * ND * 2;   // 1 MiB
  dim3 grid(NB * (NP / TP));
  if (ws_size >= ws_need) {
    cc_pre<<<dim3(NB * 8), dim3(256), 0, stream>>>(indices, codes, (unsigned char*)d_ws);
    cc_main<true><<<grid, 256, 0, stream>>>(indices, qp, cpos, codes, dsp,
                                            (const unsigned char*)d_ws, qc, sq, wt);
  } else {
    cc_main<false><<<grid, 256, 0, stream>>>(indices, qp, cpos, codes, dsp,
                                             nullptr, qc, sq, wt);
  }
}

// Round 8
// 43.205 us; speedup vs baseline: 1.1074x; 1.0307x over previous
//
#include <hip/hip_runtime.h>
#include <hip/hip_bf16.h>

#define NB 32
#define NP 4096
#define NC 128
#define ND 128
#define TP 64             // points per block (16 per wave)  [R8: 128 -> 64]
#define EPSV 1e-16f

typedef __attribute__((ext_vector_type(8))) short short8;
typedef __attribute__((ext_vector_type(4))) short short4v;
typedef __attribute__((ext_vector_type(4))) float f32x4;

__device__ __forceinline__ unsigned short f2bf(float f) {
  __hip_bfloat16 h = __float2bfloat16(f);
  return *reinterpret_cast<unsigned short*>(&h);
}

// LDS byte-offset swizzle: row-major [row][128 bf16] with XOR of (row&7)<<4.
// XOR touches bits 4-6 only -> aligned 8B/16B accesses stay contiguous.
__device__ __forceinline__ int swz(int row, int kbyte) {
  return (row * 256 + kbyte) ^ ((row & 7) << 4);
}

// Pre-kernel: pre-swizzled bf16 codes^T images ([d][c]) for the 32 gathered
// records -> d_ws. 256 blocks (8 per record), 256 threads.
__global__ void cc_pre(const int* __restrict__ indices,
                       const float* __restrict__ codes,
                       unsigned char* __restrict__ ws) {
  const int b = blockIdx.x >> 3;
  const int chunk = blockIdx.x & 7;
  const int rec = indices[b];
  const float* cb = codes + (size_t)rec * (NC * ND);
  unsigned char* wb = ws + (size_t)b * (NC * ND * 2);
  const int tid = threadIdx.x;        // 256 threads
  const int d = chunk * 16 + (tid & 15);
  const int c0 = (tid >> 4) * 8;      // 8 consecutive codes
  short8 v;
  #pragma unroll
  for (int j = 0; j < 8; ++j)
    v[j] = (short)f2bf(cb[(size_t)(c0 + j) * ND + d]);
  *(short8*)(wb + swz(d, c0 * 2)) = v;
}

// R8: R7's barrier-free structure at TP=64. Wave wv owns points
// wv*16..wv*16+15; wT is 4 x 4KB per-wave sections (16 rows each); LDS
// total 48KB -> 3 blocks/CU resident; 2048 blocks (8/CU) for finer
// interleave of ramp/compute/store phases across blocks.
template<bool PRE>
__global__ __launch_bounds__(256, 2) void cc_main(
    const int* __restrict__ indices,
    const float* __restrict__ qp,       // (B,P,3)
    const float* __restrict__ cpos,     // (R,C,3)
    const float* __restrict__ codes,    // (R,C,D)
    const void* __restrict__ dsp,       // dist_scale scalar
    const unsigned char* __restrict__ wsc, // pre-swizzled bf16 cT images
    float* __restrict__ out_qc,         // (B,P,D)
    float* __restrict__ out_sq,         // (B,P,C)
    float* __restrict__ out_wt) {       // (B,P,C)
  __shared__ __align__(16) unsigned char cT[ND * NC * 2];   // 32KB shared
  __shared__ __align__(16) unsigned char wT[TP * NC * 2];   // 16KB, 4KB/wave

  const int tid = threadIdx.x;
  const int lane = tid & 63;
  const int wv = tid >> 6;
  const int g = lane >> 4;            // point-within-quad (phase 1)
  const int l16 = lane & 15;
  const int b = blockIdx.x >> 6;
  const int p0 = (blockIdx.x & 63) * TP;
  const int rec = indices[b];
  unsigned char* wTw = wT + wv * (16 * 256); // this wave's 16-row section

  const int si = ((const int*)dsp)[0];
  const float sv = (si > 0 && si < 1000) ? (float)si : ((const float*)dsp)[0];

  // ---- cT staging first (DMA for PRE; inline else): early barrier covers it.
  if (PRE) {
    const unsigned char* src = wsc + (size_t)b * (NC * ND * 2);
    #pragma unroll
    for (int it = 0; it < 8; ++it) {
      const int off = (wv * 8 + it) * 1024;
      __builtin_amdgcn_global_load_lds(
          (const __attribute__((address_space(1))) void*)(src + off + lane * 16),
          (__attribute__((address_space(3))) void*)(cT + off),
          16, 0, 0);
    }
  } else {
    const float* cb = codes + (size_t)rec * (NC * ND);
    #pragma unroll
    for (int it = 0; it < 16; ++it) {
      int i = tid * 4 + it * 1024;
      float4 v = *reinterpret_cast<const float4*>(cb + i);
      int c = i >> 7, d0 = i & 127;
      float vv[4] = {v.x, v.y, v.z, v.w};
      #pragma unroll
      for (int j = 0; j < 4; ++j)
        *(unsigned short*)(cT + swz(d0 + j, c * 2)) = f2bf(vv[j]);
    }
  }

  // ---- per-lane code positions: lane owns codes l16*4..+3 and 64+l16*4..+3
  const float* pb0 = cpos + ((size_t)rec * NC + l16 * 4) * 3;
  const float* pb1 = cpos + ((size_t)rec * NC + 64 + l16 * 4) * 3;
  float px[8], py[8], pz[8];
  #pragma unroll
  for (int j = 0; j < 4; ++j) {
    px[j] = pb0[j * 3 + 0]; py[j] = pb0[j * 3 + 1]; pz[j] = pb0[j * 3 + 2];
    px[j + 4] = pb1[j * 3 + 0]; py[j + 4] = pb1[j * 3 + 1]; pz[j + 4] = pb1[j * 3 + 2];
  }

  // ---- q for this wave's 16 points: p = wv*16 + it*4 + g
  const size_t rowbase = (size_t)b * NP + p0;
  float qx[4], qy[4], qz[4];
  #pragma unroll
  for (int it = 0; it < 4; ++it) {
    const int p = wv * 16 + it * 4 + g;
    const float* q = qp + (rowbase + p) * 3;
    qx[it] = q[0]; qy[it] = q[1]; qz[it] = q[2];
  }

  __syncthreads();   // ONLY barrier: drains cT DMA + register loads.
                     // Zero global stores in flight here.

  // ---- phase 1: wave-local points; lane owns 8 codes (4+4 split).
  const bool s2 = (sv == 2.0f);
  #pragma unroll
  for (int it = 0; it < 4; ++it) {
    const int p = wv * 16 + it * 4 + g;
    float dd[8], wu[8];
    #pragma unroll
    for (int j = 0; j < 8; ++j) {
      const float dx = qx[it] - px[j], dy = qy[it] - py[j], dz = qz[it] - pz[j];
      dd[j] = fmaf(dx, dx, fmaf(dy, dy, dz * dz)) + EPSV;
    }
    if (s2) {
      #pragma unroll
      for (int j = 0; j < 8; ++j) wu[j] = __builtin_amdgcn_rcpf(dd[j]);
    } else {
      #pragma unroll
      for (int j = 0; j < 8; ++j) wu[j] = __powf(dd[j], -0.5f * sv);
    }
    float s = ((wu[0] + wu[1]) + (wu[2] + wu[3])) + ((wu[4] + wu[5]) + (wu[6] + wu[7]));
    s += __shfl_xor(s, 1); s += __shfl_xor(s, 2);
    s += __shfl_xor(s, 4); s += __shfl_xor(s, 8);   // within 16-lane group
    const float inv = __builtin_amdgcn_rcpf(s);

    f32x4 dlo, dhi, wlo, whi;
    #pragma unroll
    for (int j = 0; j < 4; ++j) {
      dlo[j] = dd[j]; dhi[j] = dd[j + 4];
      wlo[j] = wu[j] * inv; whi[j] = wu[j + 4] * inv;
    }
    const size_t rb = (rowbase + p) * (size_t)NC;
    *(f32x4*)(out_sq + rb + l16 * 4) = dlo;
    *(f32x4*)(out_sq + rb + 64 + l16 * 4) = dhi;
    *(f32x4*)(out_wt + rb + l16 * 4) = wlo;
    *(f32x4*)(out_wt + rb + 64 + l16 * 4) = whi;

    // bf16 weights -> this wave's wT section (local row = it*4+g)
    short4v wbl, wbh;
    #pragma unroll
    for (int j = 0; j < 4; ++j) {
      wbl[j] = (short)f2bf(wlo[j]);
      wbh[j] = (short)f2bf(whi[j]);
    }
    const int r = it * 4 + g;
    *(short4v*)(wTw + swz(r, l16 * 8)) = wbl;        // codes l16*4..+3
    *(short4v*)(wTw + swz(r, 128 + l16 * 8)) = wbh;  // codes 64+l16*4..+3
  }

  // ---- NO barrier: phase 2 reads only this wave's wT (lgkmcnt, lockstep)
  // and cT (synced at the early barrier). Phase-1 stores drain underneath.

  const int kg = lane >> 4;
  const int prl = wv * 16 + l16;       // this lane's point (local)
  f32x4 acc[8];
  #pragma unroll
  for (int mi = 0; mi < 8; ++mi) acc[mi] = (f32x4){0.f, 0.f, 0.f, 0.f};

  #pragma unroll
  for (int kk = 0; kk < NC; kk += 32) {
    const int kb = (kk + kg * 8) * 2;
    const short8 b0 = *(const short8*)(wTw + swz(l16, kb));
    #pragma unroll
    for (int mi = 0; mi < 8; ++mi) {
      const short8 a8 = *(const short8*)(cT + swz(mi * 16 + l16, kb));
      acc[mi] = __builtin_amdgcn_mfma_f32_16x16x32_bf16(a8, b0, acc[mi], 0, 0, 0);
    }
  }

  // D layout: col(=p-offset) = lane&15, row(=d-offset) = (lane>>4)*4 + reg
  float* o0 = out_qc + (rowbase + prl) * (size_t)ND + kg * 4;
  #pragma unroll
  for (int mi = 0; mi < 8; ++mi)
    *(f32x4*)(o0 + mi * 16) = acc[mi];

  (void)codes;
}

extern "C" void kernel_launch(void* const* d_in, const int* in_sizes, int n_in,
                              void* d_out, int out_size, void* d_ws, size_t ws_size,
                              hipStream_t stream) {
  const int* indices = (const int*)d_in[0];
  const float* qp = (const float*)d_in[1];
  const float* cpos = (const float*)d_in[2];
  const float* codes = (const float*)d_in[3];
  const void* dsp = d_in[4];

  float* out = (float*)d_out;
  float* qc = out;                                   // (B,P,D)
  float* sq = qc + (size_t)NB * NP * ND;             // (B,P,C)
  float* wt = sq + (size_t)NB * NP * NC;             // (B,P,C)

  const size_t ws_need = (size_t)NB * NC * ND * 2;   // 1 MiB
  dim3 grid(NB * (NP / TP));
  if (ws_size >= ws_need) {
    cc_pre<<<dim3(NB * 8), dim3(256), 0, stream>>>(indices, codes, (unsigned char*)d_ws);
    cc_main<true><<<grid, 256, 0, stream>>>(indices, qp, cpos, codes, dsp,
                                            (const unsigned char*)d_ws, qc, sq, wt);
  } else {
    cc_main<false><<<grid, 256, 0, stream>>>(indices, qp, cpos, codes, dsp,
                                             nullptr, qc, sq, wt);
  }
}

// Round 9
// 42.398 us; speedup vs baseline: 1.1285x; 1.0190x over previous
//
#include <hip/hip_runtime.h>
#include <hip/hip_bf16.h>

#define NB 32
#define NP 4096
#define NC 128
#define ND 128
#define TP 64             // points per block (16 per wave)
#define EPSV 1e-16f

typedef __attribute__((ext_vector_type(8))) short short8;
typedef __attribute__((ext_vector_type(4))) short short4v;
typedef __attribute__((ext_vector_type(4))) float f32x4;

__device__ __forceinline__ unsigned short f2bf(float f) {
  __hip_bfloat16 h = __float2bfloat16(f);
  return *reinterpret_cast<unsigned short*>(&h);
}

// LDS byte-offset swizzle for wT: row-major [row][128 bf16], XOR (row&7)<<4.
__device__ __forceinline__ int swz(int row, int kbyte) {
  return (row * 256 + kbyte) ^ ((row & 7) << 4);
}

// Pre-kernel v2: emit per-record MFMA A-FRAGMENT images (32KB/record).
// Fragment (kk, mi, lane): codes^T row d = mi*16 + (lane&15),
// elements k = kk*32 + (lane>>4)*8 .. +8, packed bf16x8 (16B).
// cc_main then reads A-operands with fully-coalesced global_load_dwordx4
// (1KB/instruction) straight from L2 — no cT LDS, no DMA, no barrier.
__global__ void cc_pre(const int* __restrict__ indices,
                       const float* __restrict__ codes,
                       unsigned char* __restrict__ ws) {
  const int b = blockIdx.x >> 3;
  const int chunk = blockIdx.x & 7;
  const int rec = indices[b];
  const float* cb = codes + (size_t)rec * (NC * ND);
  unsigned char* wb = ws + (size_t)b * (NC * ND * 2);
  const int id = chunk * 256 + threadIdx.x;   // 0..2047 fragment id
  const int lane = id & 63;
  const int l16 = lane & 15;
  const int kg = (lane >> 4) & 3;
  const int mi = (id >> 6) & 7;
  const int kk = id >> 9;
  const int d = mi * 16 + l16;
  const int cbase = kk * 32 + kg * 8;
  short8 v;
  #pragma unroll
  for (int j = 0; j < 8; ++j)
    v[j] = (short)f2bf(cb[(size_t)(cbase + j) * ND + d]);
  *(short8*)(wb + ((size_t)id * 16)) = v;     // id == (kk*8+mi)*64 + lane
}

// R9: zero-sync main kernel. No cT, no global_load_lds, no __syncthreads.
// Per-wave wT (16KB total LDS). Phase-2 A-fragments stream from the ws
// fragment image (L2-hot, coalesced), software-pipelined fA/fB.
template<bool PRE>
__global__ __launch_bounds__(256, 2) void cc_main(
    const int* __restrict__ indices,
    const float* __restrict__ qp,       // (B,P,3)
    const float* __restrict__ cpos,     // (R,C,3)
    const float* __restrict__ codes,    // (R,C,D)
    const void* __restrict__ dsp,       // dist_scale scalar
    const unsigned char* __restrict__ wsc, // fragment images (v2 layout)
    float* __restrict__ out_qc,         // (B,P,D)
    float* __restrict__ out_sq,         // (B,P,C)
    float* __restrict__ out_wt) {       // (B,P,C)
  __shared__ __align__(16) unsigned char wT[TP * NC * 2];   // 16KB, 4KB/wave

  const int tid = threadIdx.x;
  const int lane = tid & 63;
  const int wv = tid >> 6;
  const int g = lane >> 4;            // point-within-quad (phase 1)
  const int l16 = lane & 15;
  const int b = blockIdx.x >> 6;
  const int p0 = (blockIdx.x & 63) * TP;
  const int rec = indices[b];
  unsigned char* wTw = wT + wv * (16 * 256); // this wave's 16-row section

  const int si = ((const int*)dsp)[0];
  const float sv = (si > 0 && si < 1000) ? (float)si : ((const float*)dsp)[0];

  // ---- per-lane code positions: lane owns codes l16*4..+3 and 64+l16*4..+3
  const float* pb0 = cpos + ((size_t)rec * NC + l16 * 4) * 3;
  const float* pb1 = cpos + ((size_t)rec * NC + 64 + l16 * 4) * 3;
  float px[8], py[8], pz[8];
  #pragma unroll
  for (int j = 0; j < 4; ++j) {
    px[j] = pb0[j * 3 + 0]; py[j] = pb0[j * 3 + 1]; pz[j] = pb0[j * 3 + 2];
    px[j + 4] = pb1[j * 3 + 0]; py[j + 4] = pb1[j * 3 + 1]; pz[j + 4] = pb1[j * 3 + 2];
  }

  // ---- q for this wave's 16 points: p = wv*16 + it*4 + g
  const size_t rowbase = (size_t)b * NP + p0;
  float qx[4], qy[4], qz[4];
  #pragma unroll
  for (int it = 0; it < 4; ++it) {
    const int p = wv * 16 + it * 4 + g;
    const float* q = qp + (rowbase + p) * 3;
    qx[it] = q[0]; qy[it] = q[1]; qz[it] = q[2];
  }

  // ---- A-fragment source for this lane (v2 layout), and the kk=0 prefetch
  // issued BEFORE phase 1 so its L2 latency hides under the compute.
  const unsigned char* fb = wsc + (size_t)b * (NC * ND * 2) + (size_t)lane * 16;
  const float* cb = codes + (size_t)rec * (NC * ND);   // fallback path only
  short8 fA[8], fB[8];
  #pragma unroll
  for (int mi = 0; mi < 8; ++mi) {
    if (PRE) {
      fA[mi] = *(const short8*)(fb + (0 * 8 + mi) * 1024);
    } else {
      const int d = mi * 16 + l16;
      const int cbase0 = g * 8;       // kk=0
      #pragma unroll
      for (int j = 0; j < 8; ++j)
        fA[mi][j] = (short)f2bf(cb[(size_t)(cbase0 + j) * ND + d]);
    }
  }

  // ---- phase 1: wave-local points; lane owns 8 codes (4+4 split).
  const bool s2 = (sv == 2.0f);
  #pragma unroll
  for (int it = 0; it < 4; ++it) {
    const int p = wv * 16 + it * 4 + g;
    float dd[8], wu[8];
    #pragma unroll
    for (int j = 0; j < 8; ++j) {
      const float dx = qx[it] - px[j], dy = qy[it] - py[j], dz = qz[it] - pz[j];
      dd[j] = fmaf(dx, dx, fmaf(dy, dy, dz * dz)) + EPSV;
    }
    if (s2) {
      #pragma unroll
      for (int j = 0; j < 8; ++j) wu[j] = __builtin_amdgcn_rcpf(dd[j]);
    } else {
      #pragma unroll
      for (int j = 0; j < 8; ++j) wu[j] = __powf(dd[j], -0.5f * sv);
    }
    float s = ((wu[0] + wu[1]) + (wu[2] + wu[3])) + ((wu[4] + wu[5]) + (wu[6] + wu[7]));
    s += __shfl_xor(s, 1); s += __shfl_xor(s, 2);
    s += __shfl_xor(s, 4); s += __shfl_xor(s, 8);   // within 16-lane group
    const float inv = __builtin_amdgcn_rcpf(s);

    f32x4 dlo, dhi, wlo, whi;
    #pragma unroll
    for (int j = 0; j < 4; ++j) {
      dlo[j] = dd[j]; dhi[j] = dd[j + 4];
      wlo[j] = wu[j] * inv; whi[j] = wu[j + 4] * inv;
    }
    const size_t rb = (rowbase + p) * (size_t)NC;
    *(f32x4*)(out_sq + rb + l16 * 4) = dlo;
    *(f32x4*)(out_sq + rb + 64 + l16 * 4) = dhi;
    *(f32x4*)(out_wt + rb + l16 * 4) = wlo;
    *(f32x4*)(out_wt + rb + 64 + l16 * 4) = whi;

    short4v wbl, wbh;
    #pragma unroll
    for (int j = 0; j < 4; ++j) {
      wbl[j] = (short)f2bf(wlo[j]);
      wbh[j] = (short)f2bf(whi[j]);
    }
    const int r = it * 4 + g;
    *(short4v*)(wTw + swz(r, l16 * 8)) = wbl;        // codes l16*4..+3
    *(short4v*)(wTw + swz(r, 128 + l16 * 8)) = wbh;  // codes 64+l16*4..+3
  }

  // ---- phase 2: NO barrier anywhere. wT is wave-local (lgkmcnt ordering);
  // A-fragments stream from L2, pipelined one k-step ahead.
  const int kg = lane >> 4;
  const int prl = wv * 16 + l16;       // this lane's point (local)
  f32x4 acc[8];
  #pragma unroll
  for (int mi = 0; mi < 8; ++mi) acc[mi] = (f32x4){0.f, 0.f, 0.f, 0.f};

  #define LOADF(dst, kknext)                                                   \
    _Pragma("unroll")                                                          \
    for (int mi = 0; mi < 8; ++mi) {                                           \
      if (PRE) {                                                               \
        dst[mi] = *(const short8*)(fb + ((kknext) * 8 + mi) * 1024);           \
      } else {                                                                 \
        const int d = mi * 16 + l16;                                           \
        const int cb0 = (kknext) * 32 + g * 8;                                 \
        _Pragma("unroll")                                                      \
        for (int j = 0; j < 8; ++j)                                            \
          dst[mi][j] = (short)f2bf(cb[(size_t)(cb0 + j) * ND + d]);            \
      }                                                                        \
    }

  #define COMPUTE(src, kk)                                                     \
    {                                                                          \
      const int kb = ((kk) * 32 + kg * 8) * 2;                                 \
      const short8 b0 = *(const short8*)(wTw + swz(l16, kb));                  \
      _Pragma("unroll")                                                        \
      for (int mi = 0; mi < 8; ++mi)                                           \
        acc[mi] = __builtin_amdgcn_mfma_f32_16x16x32_bf16(src[mi], b0,         \
                                                          acc[mi], 0, 0, 0);   \
    }

  LOADF(fB, 1)
  COMPUTE(fA, 0)
  LOADF(fA, 2)
  COMPUTE(fB, 1)
  LOADF(fB, 3)
  COMPUTE(fA, 2)
  COMPUTE(fB, 3)

  #undef LOADF
  #undef COMPUTE

  // D layout: col(=p-offset) = lane&15, row(=d-offset) = (lane>>4)*4 + reg
  float* o0 = out_qc + (rowbase + prl) * (size_t)ND + kg * 4;
  #pragma unroll
  for (int mi = 0; mi < 8; ++mi)
    *(f32x4*)(o0 + mi * 16) = acc[mi];
}

extern "C" void kernel_launch(void* const* d_in, const int* in_sizes, int n_in,
                              void* d_out, int out_size, void* d_ws, size_t ws_size,
                              hipStream_t stream) {
  const int* indices = (const int*)d_in[0];
  const float* qp = (const float*)d_in[1];
  const float* cpos = (const float*)d_in[2];
  const float* codes = (const float*)d_in[3];
  const void* dsp = d_in[4];

  float* out = (float*)d_out;
  float* qc = out;                                   // (B,P,D)
  float* sq = qc + (size_t)NB * NP * ND;             // (B,P,C)
  float* wt = sq + (size_t)NB * NP * NC;             // (B,P,C)

  const size_t ws_need = (size_t)NB * NC * ND * 2;   // 1 MiB
  dim3 grid(NB * (NP / TP));
  if (ws_size >= ws_need) {
    cc_pre<<<dim3(NB * 8), dim3(256), 0, stream>>>(indices, codes, (unsigned char*)d_ws);
    cc_main<true><<<grid, 256, 0, stream>>>(indices, qp, cpos, codes, dsp,
                                            (const unsigned char*)d_ws, qc, sq, wt);
  } else {
    cc_main<false><<<grid, 256, 0, stream>>>(indices, qp, cpos, codes, dsp,
                                             nullptr, qc, sq, wt);
  }
}